// Round 6
// baseline (480.874 us; speedup 1.0000x reference)
//
#include <hip/hip_runtime.h>

// GradientInputLayer: B=64, C=2, L=64, N=16, BIN=360//16=22, EPS=1e-5
// x: (64, 2*64^3) f32 in {0,1}; out: (64,2,16,16) f32
//
// *** R6 = MEASUREMENT ROUND ***
// Scatter is dispatched 8x into 8 disjoint g buffers; norm reads g[0] (output
// identical). scatter_dur = (dur_R6 - dur_R5)/7 - launch_gap. Decides whether
// scatter is at its memory floor (declare roofline) or issue-limited
// (restructure).
//
// ws layout: [0, 262144)        uint8 bin table tab[i*4096 + j*64 + k]
//            [262144, 1310720)  float g[8][128*256] accumulators (pair-major)
//
// R3 lesson: NO device-scope fences / nontemporal loads in the per-block path.
// R4 lesson: inter-wave LDS-atomic serialization negligible.
// R5 lesson: load-latency pipelining + dual RLE chains neutral.

#define BINS_PAD 80   // real bins are 0..68 (ax,az in 0..4); 69 = flush sentinel

__global__ __launch_bounds__(256)
void bin_table_kernel(unsigned char* __restrict__ tab, float* __restrict__ g) {
    int v = blockIdx.x * 256 + threadIdx.x;          // 0..262143
    int i = v >> 12, j = (v >> 6) & 63, k = v & 63;
    double xc2 = (double)(j * j + k * k);            // x_comp^2
    double zc2 = (double)(i * i + j * j);            // z_comp^2
    double i2  = (double)(i * i);
    double k2  = (double)(k * k);
    // tan^2 of 22/44/66/88 degrees; fold at compile time in double.
    const double T1 = 0.4040262258351568  * 0.4040262258351568;
    const double T2 = 0.9656887748070740  * 0.9656887748070740;
    const double T3 = 2.2460367739042161  * 2.2460367739042161;
    const double T4 = 28.636253282915602  * 28.636253282915602;
    // ax = floor(atan2(xc, i)*deg/22) == #{m : xc^2 > i^2 tan^2(22m)}; strict >
    // handles every atan2(0,*)/atan2(*,0) edge case exactly (verified absmax 0.0).
    int ax = (xc2 > i2 * T1) + (xc2 > i2 * T2) + (xc2 > i2 * T3) + (xc2 > i2 * T4);
    int az = (k2 > zc2 * T1) + (k2 > zc2 * T2) + (k2 > zc2 * T3) + (k2 > zc2 * T4);
    tab[v] = (unsigned char)(ax * 16 + az);
    g[v] = 0.0f;                     // zeroes all 8 replica buffers (262144 floats)
}

// 256-thread blocks (4 waves); block = (pair p, 4 i-slabs), wave w owns slab i.
// R5 body unchanged (verified absmax 0.0): 2-stage SW pipeline, dual RLE
// chains, wave-private LDS hist, one <=80-bin global-atomic flush per block.
__global__ __launch_bounds__(256)
void scatter_kernel(const float4* __restrict__ x4,
                    const unsigned int* __restrict__ tabu,
                    float* __restrict__ g) {
    __shared__ float hist[4][BINS_PAD];
    int tid = threadIdx.x;
    int p   = blockIdx.x >> 4;               // (b,c) pair 0..127
    int w   = tid >> 6;                      // wave 0..3
    int t   = tid & 63;                      // lane
    int i   = (blockIdx.x & 15) * 4 + w;     // i-slab 0..63
    for (int n = tid; n < 4 * BINS_PAD; n += 256) ((float*)hist)[n] = 0.0f;
    __syncthreads();

    float* whist = hist[w];

    const float4*       xs = x4   + (size_t)p * 65536 + (size_t)i * 1024;
    const unsigned int* ts = tabu + i * 1024;

    int thi = t >> 4;                 // j sub-index 0..3
    int k0  = (t & 15) * 4;           // this lane's k base (lane-constant)
    float kk0 = (float)(k0 * k0);
    float kk1 = (float)((k0 + 1) * (k0 + 1));
    float kk2 = (float)((k0 + 2) * (k0 + 2));
    float kk3 = (float)((k0 + 3) * (k0 + 3));
    int i2 = i * i;

    float accA = 0.0f, accB = 0.0f;
    int   curA = 69,   curB = 69;     // sentinel bin (never produced; stays ~0)

    float4       xv = xs[t];
    unsigned int u  = ts[t];

    #pragma unroll
    for (int m = 0; m < 16; ++m) {
        float4       nxv;
        unsigned int nu;
        if (m < 15) {                 // uniform branch; keeps next loads in flight
            nxv = xs[(m + 1) * 64 + t];
            nu  = ts[(m + 1) * 64 + t];
        }
        int   j   = m * 4 + thi;      // j-line within slab
        float r2f = (float)(i2 + j * j);
        {   int bA = u & 255;
            int bB = (u >> 16) & 255;
            float vA = xv.x * sqrtf(r2f + kk0);
            float vB = xv.z * sqrtf(r2f + kk2);
            if (bA != curA) { atomicAdd(&whist[curA], accA); curA = bA; accA = vA; }
            else            { accA += vA; }
            if (bB != curB) { atomicAdd(&whist[curB], accB); curB = bB; accB = vB; }
            else            { accB += vB; }
        }
        {   int bA = (u >> 8) & 255;
            int bB = (u >> 24);
            float vA = xv.y * sqrtf(r2f + kk1);
            float vB = xv.w * sqrtf(r2f + kk3);
            if (bA != curA) { atomicAdd(&whist[curA], accA); curA = bA; accA = vA; }
            else            { accA += vA; }
            if (bB != curB) { atomicAdd(&whist[curB], accB); curB = bB; accB = vB; }
            else            { accB += vB; }
        }
        xv = nxv; u = nu;
    }
    atomicAdd(&whist[curA], accA);
    atomicAdd(&whist[curB], accB);
    __syncthreads();

    if (tid < BINS_PAD) {
        float hv = hist[0][tid] + hist[1][tid] + hist[2][tid] + hist[3][tid];
        if (hv != 0.0f) atomicAdd(&g[p * 256 + tid], hv);
    }
}

// Single block: per-channel mean/var over (B, N, N) = 16384 values in double,
// then fused scale/shift write of all 32768 outputs.
__global__ __launch_bounds__(1024)
void norm_kernel(const float* __restrict__ g,
                 const float* __restrict__ gamma,
                 const float* __restrict__ beta,
                 float* __restrict__ out) {
    __shared__ double red[16][4];
    __shared__ float  coef[4];        // sc0, sc1, sh0, sh1
    int t = threadIdx.x;
    float vals[32];
    double s0 = 0.0, s1 = 0.0, q0 = 0.0, q1 = 0.0;
    #pragma unroll
    for (int n = 0; n < 32; ++n) {
        int idx = t + n * 1024;
        float v = g[idx];
        vals[n] = v;
        double vd = (double)v;
        if ((idx >> 8) & 1) { s1 += vd; q1 += vd * vd; }
        else                { s0 += vd; q0 += vd * vd; }
    }
    #pragma unroll
    for (int off = 32; off > 0; off >>= 1) {
        s0 += __shfl_down(s0, off);
        s1 += __shfl_down(s1, off);
        q0 += __shfl_down(q0, off);
        q1 += __shfl_down(q1, off);
    }
    int wave = t >> 6;
    if ((t & 63) == 0) {
        red[wave][0] = s0; red[wave][1] = s1; red[wave][2] = q0; red[wave][3] = q1;
    }
    __syncthreads();
    if (t == 0) {
        double S0 = 0, S1 = 0, Q0 = 0, Q1 = 0;
        for (int wv = 0; wv < 16; ++wv) {
            S0 += red[wv][0]; S1 += red[wv][1]; Q0 += red[wv][2]; Q1 += red[wv][3];
        }
        const double inv_n = 1.0 / 16384.0;
        double m0 = S0 * inv_n, m1 = S1 * inv_n;
        double v0 = Q0 * inv_n - m0 * m0;
        double v1 = Q1 * inv_n - m1 * m1;
        double r0 = 1.0 / sqrt(v0 + 1e-5);
        double r1 = 1.0 / sqrt(v1 + 1e-5);
        float g0 = gamma[0], g1 = gamma[1], b0 = beta[0], b1 = beta[1];
        coef[0] = (float)r0 * g0;
        coef[1] = (float)r1 * g1;
        coef[2] = b0 - (float)(m0 * r0) * g0;
        coef[3] = b1 - (float)(m1 * r1) * g1;
    }
    __syncthreads();
    float sc0 = coef[0], sc1 = coef[1], sh0 = coef[2], sh1 = coef[3];
    #pragma unroll
    for (int n = 0; n < 32; ++n) {
        int idx = t + n * 1024;
        int c = (idx >> 8) & 1;
        out[idx] = vals[n] * (c ? sc1 : sc0) + (c ? sh1 : sh0);
    }
}

extern "C" void kernel_launch(void* const* d_in, const int* in_sizes, int n_in,
                              void* d_out, int out_size, void* d_ws, size_t ws_size,
                              hipStream_t stream) {
    const float* x     = (const float*)d_in[0];
    const float* gamma = (const float*)d_in[1];
    const float* beta  = (const float*)d_in[2];
    float* out = (float*)d_out;

    unsigned char* tab = (unsigned char*)d_ws;
    float*         g   = (float*)((char*)d_ws + 262144);

    bin_table_kernel<<<1024, 256, 0, stream>>>(tab, g);
    // 8 identical scatters into disjoint g buffers: Δdur/7 = per-scatter time.
    for (int rep = 0; rep < 8; ++rep) {
        scatter_kernel<<<2048, 256, 0, stream>>>((const float4*)x,
                                                 (const unsigned int*)tab,
                                                 g + (size_t)rep * 32768);
    }
    norm_kernel<<<1, 1024, 0, stream>>>(g, gamma, beta, out);
}

// Round 7
// 206.562 us; speedup vs baseline: 2.3280x; 2.3280x over previous
//
#include <hip/hip_runtime.h>

// GradientInputLayer: B=64, C=2, L=64, N=16, BIN=360//16=22, EPS=1e-5
// x: (64, 2*64^3) f32 in {0,1}; out: (64,2,16,16) f32
//
// ws layout: [0, 262144)      uint8 bin table tab[i*4096 + j*64 + k]
//            [262144, 393216) float g[128*256] accumulator (pair-major)
//
// R3: NO device-scope fences / nontemporal loads in per-block path.
// R4: inter-wave LDS-atomic privatization neutral.
// R5: load pipelining + dual RLE chains neutral.
// R6 measurement: scatter = 38.8us even with x L3-hot => NOT BW-bound; the
//   cost is flush count/divergence (old layout changed j every step => bin
//   changed nearly every element => ~28 flushes/lane). Fix: RLE along k
//   (bin monotone in k, <=8 changes per 64-k line).

#define BINS_PAD 80   // real bins are 0..68 (ax,az in 0..4); 69 = flush sentinel

__global__ __launch_bounds__(256)
void bin_table_kernel(unsigned char* __restrict__ tab, float* __restrict__ g) {
    int v = blockIdx.x * 256 + threadIdx.x;          // 0..262143
    int i = v >> 12, j = (v >> 6) & 63, k = v & 63;
    double xc2 = (double)(j * j + k * k);            // x_comp^2
    double zc2 = (double)(i * i + j * j);            // z_comp^2
    double i2  = (double)(i * i);
    double k2  = (double)(k * k);
    // tan^2 of 22/44/66/88 degrees; fold at compile time in double.
    const double T1 = 0.4040262258351568  * 0.4040262258351568;
    const double T2 = 0.9656887748070740  * 0.9656887748070740;
    const double T3 = 2.2460367739042161  * 2.2460367739042161;
    const double T4 = 28.636253282915602  * 28.636253282915602;
    // ax = floor(atan2(xc, i)*deg/22) == #{m : xc^2 > i^2 tan^2(22m)}; strict >
    // handles every atan2(0,*)/atan2(*,0) edge case exactly (verified absmax 0.0).
    int ax = (xc2 > i2 * T1) + (xc2 > i2 * T2) + (xc2 > i2 * T3) + (xc2 > i2 * T4);
    int az = (k2 > zc2 * T1) + (k2 > zc2 * T2) + (k2 > zc2 * T3) + (k2 > zc2 * T4);
    tab[v] = (unsigned char)(ax * 16 + az);
    if (v < 32768) g[v] = 0.0f;                      // zero accumulator (ws is poisoned)
}

// Block = (pair p, i-slab), 256 threads (4 waves). Thread owns j = tid>>2 and
// k-segment (tid&3)*16..+15: RLE along k, where the bin is monotone (<=8
// changes per full line, ~2 per 16-segment). All loads coalesced: tab uint4
// (16 B/thread contiguous), x 4x float4 at 4*tid+q. Wave-private LDS hist;
// one <=80-bin global-atomic flush per block.
__global__ __launch_bounds__(256)
void scatter_kernel(const float4* __restrict__ x4,
                    const uint4* __restrict__ tab4,
                    float* __restrict__ g) {
    __shared__ float hist[4][BINS_PAD];
    int tid = threadIdx.x;
    int p   = blockIdx.x >> 6;               // (b,c) pair 0..127
    int i   = blockIdx.x & 63;               // i-slab 0..63
    int w   = tid >> 6;                      // wave 0..3
    for (int n = tid; n < 4 * BINS_PAD; n += 256) ((float*)hist)[n] = 0.0f;
    __syncthreads();

    float* whist = hist[w];

    int j  = tid >> 2;                       // j-line 0..63
    int k0 = (tid & 3) * 16;                 // k-segment base

    // issue all 5 loads up front (coalesced; overlap with setup)
    const float4* xs = x4 + (size_t)p * 65536 + (size_t)i * 1024;
    uint4  tb  = tab4[i * 256 + tid];
    float4 xv0 = xs[4 * tid + 0];
    float4 xv1 = xs[4 * tid + 1];
    float4 xv2 = xs[4 * tid + 2];
    float4 xv3 = xs[4 * tid + 3];

    float r2f = (float)(i * i + j * j);      // exact (< 2^24)

    float acc = 0.0f;
    int   cur = 69;                          // sentinel bin (stays ~0 in pad)

    float4       xq[4] = {xv0, xv1, xv2, xv3};
    unsigned int uq[4] = {tb.x, tb.y, tb.z, tb.w};

    #pragma unroll
    for (int q = 0; q < 4; ++q) {
        unsigned int u = uq[q];
        float kq = (float)(k0 + q * 4);
        #pragma unroll
        for (int e = 0; e < 4; ++e) {
            float k  = kq + (float)e;
            float xe = (e == 0) ? xq[q].x : (e == 1) ? xq[q].y : (e == 2) ? xq[q].z : xq[q].w;
            float val = xe * sqrtf(r2f + k * k);
            int   b   = (u >> (8 * e)) & 255;
            if (b != cur) { atomicAdd(&whist[cur], acc); cur = b; acc = val; }
            else          { acc += val; }
        }
    }
    atomicAdd(&whist[cur], acc);
    __syncthreads();

    if (tid < BINS_PAD) {
        float hv = hist[0][tid] + hist[1][tid] + hist[2][tid] + hist[3][tid];
        if (hv != 0.0f) atomicAdd(&g[p * 256 + tid], hv);
    }
}

// Single block: per-channel mean/var over (B, N, N) = 16384 values in double,
// then fused scale/shift write of all 32768 outputs.
__global__ __launch_bounds__(1024)
void norm_kernel(const float* __restrict__ g,
                 const float* __restrict__ gamma,
                 const float* __restrict__ beta,
                 float* __restrict__ out) {
    __shared__ double red[16][4];
    __shared__ float  coef[4];        // sc0, sc1, sh0, sh1
    int t = threadIdx.x;
    float vals[32];
    double s0 = 0.0, s1 = 0.0, q0 = 0.0, q1 = 0.0;
    #pragma unroll
    for (int n = 0; n < 32; ++n) {
        int idx = t + n * 1024;
        float v = g[idx];
        vals[n] = v;
        double vd = (double)v;
        if ((idx >> 8) & 1) { s1 += vd; q1 += vd * vd; }
        else                { s0 += vd; q0 += vd * vd; }
    }
    #pragma unroll
    for (int off = 32; off > 0; off >>= 1) {
        s0 += __shfl_down(s0, off);
        s1 += __shfl_down(s1, off);
        q0 += __shfl_down(q0, off);
        q1 += __shfl_down(q1, off);
    }
    int wave = t >> 6;
    if ((t & 63) == 0) {
        red[wave][0] = s0; red[wave][1] = s1; red[wave][2] = q0; red[wave][3] = q1;
    }
    __syncthreads();
    if (t == 0) {
        double S0 = 0, S1 = 0, Q0 = 0, Q1 = 0;
        for (int wv = 0; wv < 16; ++wv) {
            S0 += red[wv][0]; S1 += red[wv][1]; Q0 += red[wv][2]; Q1 += red[wv][3];
        }
        const double inv_n = 1.0 / 16384.0;
        double m0 = S0 * inv_n, m1 = S1 * inv_n;
        double v0 = Q0 * inv_n - m0 * m0;
        double v1 = Q1 * inv_n - m1 * m1;
        double r0 = 1.0 / sqrt(v0 + 1e-5);
        double r1 = 1.0 / sqrt(v1 + 1e-5);
        float g0 = gamma[0], g1 = gamma[1], b0 = beta[0], b1 = beta[1];
        coef[0] = (float)r0 * g0;
        coef[1] = (float)r1 * g1;
        coef[2] = b0 - (float)(m0 * r0) * g0;
        coef[3] = b1 - (float)(m1 * r1) * g1;
    }
    __syncthreads();
    float sc0 = coef[0], sc1 = coef[1], sh0 = coef[2], sh1 = coef[3];
    #pragma unroll
    for (int n = 0; n < 32; ++n) {
        int idx = t + n * 1024;
        int c = (idx >> 8) & 1;
        out[idx] = vals[n] * (c ? sc1 : sc0) + (c ? sh1 : sh0);
    }
}

extern "C" void kernel_launch(void* const* d_in, const int* in_sizes, int n_in,
                              void* d_out, int out_size, void* d_ws, size_t ws_size,
                              hipStream_t stream) {
    const float* x     = (const float*)d_in[0];
    const float* gamma = (const float*)d_in[1];
    const float* beta  = (const float*)d_in[2];
    float* out = (float*)d_out;

    unsigned char* tab = (unsigned char*)d_ws;
    float*         g   = (float*)((char*)d_ws + 262144);

    bin_table_kernel<<<1024, 256, 0, stream>>>(tab, g);
    scatter_kernel<<<8192, 256, 0, stream>>>((const float4*)x, (const uint4*)tab, g);
    norm_kernel<<<1, 1024, 0, stream>>>(g, gamma, beta, out);
}